// Round 13
// baseline (170.748 us; speedup 1.0000x reference)
//
#include <hip/hip_runtime.h>
#include <hip/hip_bf16.h>

#define BB 512
#define CC 112
#define DD 128
#define HH 8
#define HD 16
#define KK 8
#define QS 1792  // per-head u16 stride in QO/KL (112*16)

typedef unsigned short u16;
typedef short short8 __attribute__((ext_vector_type(8)));
typedef float f32x4 __attribute__((ext_vector_type(4)));
typedef float f32x16 __attribute__((ext_vector_type(16)));

#define MFMA16(a, b, c) __builtin_amdgcn_mfma_f32_16x16x32_bf16(a, b, c, 0, 0, 0)
#define MFMA32(a, b, c) __builtin_amdgcn_mfma_f32_32x32x16_bf16(a, b, c, 0, 0, 0)

__device__ inline u16 f2bf(float f) {
  union { float f; unsigned u; } v{f};
  unsigned r = (v.u + 0x7FFFu + ((v.u >> 16) & 1u)) >> 16;
  return (u16)r;
}
__device__ inline float bf2f(u16 u) {
  union { unsigned u; float f; } v;
  v.u = ((unsigned)u) << 16;
  return v.f;
}
__device__ inline unsigned pk2(float a, float b) {
  __hip_bfloat162 h = __float22bfloat162_rn(float2{a, b});
  union { __hip_bfloat162 h; unsigned u; } v{h};
  return v.u;
}

// lane[i] <-> lane[i^32] exchange via v_permlane32_swap_b32 (VALU, no LDS
// pipe). Validated on-harness R1-R7, R11, R12.
__device__ inline unsigned permx32(unsigned x) {
  unsigned a = x, b = x;
  asm("v_permlane32_swap_b32 %0, %1" : "+v"(a), "+v"(b));
  return (threadIdx.x & 32) ? a : b;
}
__device__ inline float permx32f(float x) {
  union { float f; unsigned u; } v{x};
  v.u = permx32(v.u);
  return v.f;
}

// ---------------------------------------------------------------------------
// K1: conv+GELU+BN+residual -> bf16 src_b (global). 1024 blocks x 256 thr
// (2 blocks/batch, 56 rows each; R11/R12-validated). Threads 224..255 of
// each block convert 32 weight fp32-pairs -> bf16 w_b (1024 x 32 = 32768).
// ---------------------------------------------------------------------------
__global__ __launch_bounds__(256, 4) void k_conv(
    const float* __restrict__ x, const float* __restrict__ cw,
    const float* __restrict__ cb, const float* __restrict__ bg,
    const float* __restrict__ bb_, const float* __restrict__ bm,
    const float* __restrict__ bv, const float* __restrict__ wq,
    const float* __restrict__ wk, const float* __restrict__ wv,
    const float* __restrict__ wo, u16* __restrict__ src_b,
    u16* __restrict__ w_b) {
  const int bid = blockIdx.x;
  const int b = bid >> 1, half = bid & 1;
  const int t = threadIdx.x;
  const int tg = t >> 2, sub = t & 3;
  if (tg < 56) {
    const int row = half * 56 + tg, ch = row;
    const float4 w0 = *(const float4*)(cw + ch * KK);
    const float4 w1 = *(const float4*)(cw + ch * KK + 4);
    const float cbv = cb[ch];
    const float bscale = bg[ch] * rsqrtf(bv[ch] + 1e-5f);
    const float bmv = bm[ch], bbv = bb_[ch];
    const float* __restrict__ xr = x + ((size_t)b * CC + row) * DD;
    float in[40];  // cols sub*32-4 .. sub*32+35
#pragma unroll
    for (int f = 0; f < 10; ++f) {
      const int fi = 8 * sub - 1 + f;
      float4 vv = {0.f, 0.f, 0.f, 0.f};
      if (fi >= 0 && fi < 32) vv = ((const float4*)xr)[fi];
      in[f * 4 + 0] = vv.x; in[f * 4 + 1] = vv.y;
      in[f * 4 + 2] = vv.z; in[f * 4 + 3] = vv.w;
    }
    unsigned pkv[16];
#pragma unroll
    for (int i2 = 0; i2 < 16; ++i2) {
      float oo[2];
#pragma unroll
      for (int j = 0; j < 2; ++j) {
        const int i = i2 * 2 + j;
        float a = 0.f;
        a = fmaf(in[i + 1], w0.x, a);
        a = fmaf(in[i + 2], w0.y, a);
        a = fmaf(in[i + 3], w0.z, a);
        a = fmaf(in[i + 4], w0.w, a);
        a = fmaf(in[i + 5], w1.x, a);
        a = fmaf(in[i + 6], w1.y, a);
        a = fmaf(in[i + 7], w1.z, a);
        a = fmaf(in[i + 8], w1.w, a);
        a += cbv;
        // GELU tanh-form via sigma (validated, absmax unchanged)
        const float u = fmaf(0.044715f * a, a, 1.0f);
        const float e = __expf(a * u * -1.5957691216f);
        const float g2 = a * __frcp_rn(1.f + e);
        oo[j] = in[i + 4] + (g2 - bmv) * bscale + bbv;  // x + BN(GELU)
      }
      pkv[i2] = pk2(oo[0], oo[1]);
    }
    uint4* gsr = (uint4*)(src_b + ((size_t)b * CC + row) * DD + sub * 32);
#pragma unroll
    for (int k4 = 0; k4 < 4; ++k4) gsr[k4] = ((uint4*)pkv)[k4];
  } else if (t >= 224) {
    // weight conversion: pair index p covers 2 floats.
    const int p = bid * 32 + (t - 224);       // [0, 32768)
    const int sel = p >> 13, off = p & 8191;  // matrix, pair-within-matrix
    const float* w = (sel == 0) ? wq : (sel == 1) ? wk : (sel == 2) ? wv : wo;
    const float2 v = ((const float2*)w)[off];
    ((unsigned*)w_b)[p] = pk2(v.x, v.y);
  }
}

// ---------------------------------------------------------------------------
// K2: QKV + attention + out-proj + LN, one block per batch, 512 thr = 8
// waves, LDS 57.3 KB -> 2 blocks/CU, all 512 blocks resident (one round).
// R12 (S4) core + R13 deltas, all local and arithmetic-identity-safe:
//  (1) dual PV accumulators (kt even->oaccA, odd->oaccB, summed at end) --
//      splits the 7-long dependent MFMA chain (the kernel's longest serial
//      dependency, ~250-450 stall cyc/qt) into 4+3;
//  (2) biases folded into MFMA accumulator init (bias is uniform across the
//      4 acc slots since it depends only on the lane's output column).
// Phase A (QKV), wave = head h: weight B-frags in regs; A-frags from global
//   src_b (L2-hot); Q -> LDS QO[h], K -> LDS KL[h], V -> registers pv[14].
// Phase B (attn), same wave: 4 query-tiles; max + exp + normalize-in-pack;
//   P exchanged via permlane32_swap; PV B-frag = own pv + shfl_xor(pv,16);
//   O overwrites the wave's own (dead) Q rows in QO.
// __syncthreads (the kernel's only barrier).
// Phase C (out-proj+LN), waves 0..6, M-tile = wave: A-frags from QO across
//   heads; Wo bf16 from w_b; residual from src_b; LayerNorm -> fp32 out.
// ---------------------------------------------------------------------------
__global__ __launch_bounds__(512, 4) void k_main(
    const u16* __restrict__ src_b, const u16* __restrict__ w_b,
    const float* __restrict__ bq, const float* __restrict__ bk,
    const float* __restrict__ bvv, const float* __restrict__ bo,
    const float* __restrict__ lg, const float* __restrict__ lb,
    float* __restrict__ out) {
  __shared__ __attribute__((aligned(16))) u16 QO[HH * CC * HD];  // 28672 B
  __shared__ __attribute__((aligned(16))) u16 KL[HH * CC * HD];  // 28672 B
  const int b = blockIdx.x;
  const int t = threadIdx.x;
  const int wave = t >> 6, lane = t & 63;
  const int h = wave;
  const int quad = lane >> 4, n = lane & 15;

  // ---- phase A: QKV ----
  unsigned pv[14];
  {
    short8 Wq[4], Wk[4], Wv[4];
#pragma unroll
    for (int kf = 0; kf < 4; ++kf) {
      const int wi = (h * 16 + n) * DD + kf * 32 + quad * 8;
      Wq[kf] = *(const short8*)(w_b + wi);
      Wk[kf] = *(const short8*)(w_b + 16384 + wi);
      Wv[kf] = *(const short8*)(w_b + 32768 + wi);
    }
    const float bqv = bq[h * 16 + n];
    const float bkv = bk[h * 16 + n];
    const float bvv2 = bvv[h * 16 + n];
    u16* qoh = QO + h * QS;
    u16* klh = KL + h * QS;
    const u16* __restrict__ sp = src_b + (size_t)b * CC * DD;
#pragma unroll
    for (int mt = 0; mt < 7; ++mt) {
      short8 A[4];
#pragma unroll
      for (int kf = 0; kf < 4; ++kf)
        A[kf] = *(const short8*)(sp + (mt * 16 + n) * DD + kf * 32 + quad * 8);
      // R13: biases folded into accumulator init (uniform across acc slots)
      f32x4 aq = {bqv, bqv, bqv, bqv};
      f32x4 ak = {bkv, bkv, bkv, bkv};
      f32x4 av = {bvv2, bvv2, bvv2, bvv2};
#pragma unroll
      for (int kf = 0; kf < 4; ++kf) {
        aq = MFMA16(A[kf], Wq[kf], aq);
        ak = MFMA16(A[kf], Wk[kf], ak);
        av = MFMA16(A[kf], Wv[kf], av);
      }
      const int row0 = mt * 16 + quad * 4;
#pragma unroll
      for (int r = 0; r < 4; ++r) {
        qoh[(row0 + r) * HD + n] = f2bf(aq[r]);
        klh[(row0 + r) * HD + n] = f2bf(ak[r]);
      }
      // V rows 16mt+4quad+{0..3}, col n stay in regs as bf16 pairs
      pv[2 * mt] = pk2(av[0], av[1]);
      pv[2 * mt + 1] = pk2(av[2], av[3]);
    }
  }

  // ---- phase B: attention (no barrier needed: Q/K/V self-produced) ----
  {
    const int lo = lane & 31, hi = lane >> 5, hi8 = hi * 8;
    u16* qoh = QO + h * QS;
    const u16* klh = KL + h * QS;
    for (int qt = 0; qt < 4; ++qt) {
      const int qt0 = qt * 32;
      short8 Bq = {};
      if (qt0 + lo < CC) Bq = *(const short8*)(qoh + (qt0 + lo) * HD + hi8);
      f32x16 sa[4];
#pragma unroll
      for (int mt = 0; mt < 4; ++mt) {
        short8 Ak = {};
        const int key = mt * 32 + lo;
        if (key < CC) Ak = *(const short8*)(klh + key * HD + hi8);
        f32x16 z = {};
        sa[mt] = MFMA32(Ak, Bq, z);
      }
      // lane holds S^T[key=32mt+(r&3)+8(r>>2)+4hi][query=qt0+lo];
      // valid: mt<3 all regs, mt=3 regs 0..7 (keys 96..111).
      const float C1 = 0.25f * 1.44269504088896341f;  // SCALE * log2(e)
      float mxp[4] = {-1e30f, -1e30f, -1e30f, -1e30f};  // 4-way ILP chains
#pragma unroll
      for (int mt = 0; mt < 4; ++mt) {
        const int rmax = (mt == 3) ? 8 : 16;
#pragma unroll
        for (int r = 0; r < 16; ++r)
          if (r < rmax) mxp[r & 3] = fmaxf(mxp[r & 3], sa[mt][r]);
      }
      float mx = fmaxf(fmaxf(mxp[0], mxp[1]), fmaxf(mxp[2], mxp[3]));
      mx = fmaxf(mx, permx32f(mx));
      const float mxc = mx * C1;
      float sp4[4] = {0.f, 0.f, 0.f, 0.f};
#pragma unroll
      for (int mt = 0; mt < 4; ++mt) {
        const int rmax = (mt == 3) ? 8 : 16;
#pragma unroll
        for (int r = 0; r < 16; ++r)
          if (r < rmax) {
            const float p = exp2f(fmaf(sa[mt][r], C1, -mxc));
            sa[mt][r] = p;
            sp4[r & 3] += p;
          }
      }
      float sum = (sp4[0] + sp4[1]) + (sp4[2] + sp4[3]);
      sum += permx32f(sum);
      const float rinv = 1.f / sum;
      unsigned U0[4][4], U1[4][4];
#pragma unroll
      for (int mt = 0; mt < 4; ++mt) {
        const int rqmax = (mt == 3) ? 2 : 4;
#pragma unroll
        for (int rq = 0; rq < 4; ++rq)
          if (rq < rqmax) {
            U0[mt][rq] =
                pk2(sa[mt][4 * rq + 0] * rinv, sa[mt][4 * rq + 1] * rinv);
            U1[mt][rq] =
                pk2(sa[mt][4 * rq + 2] * rinv, sa[mt][4 * rq + 3] * rinv);
          }
      }
      // R13: dual accumulators break the 7-long dependent PV MFMA chain
      f32x16 oaccA = {};
      f32x16 oaccB = {};
#pragma unroll
      for (int kt = 0; kt < 7; ++kt) {
        const int mt = kt >> 1;
        const int c = 2 * (kt & 1);
        const unsigned own0 = hi ? U0[mt][c + 1] : U0[mt][c];
        const unsigned own1 = hi ? U1[mt][c + 1] : U1[mt][c];
        const unsigned snd0 = hi ? U0[mt][c] : U0[mt][c + 1];
        const unsigned snd1 = hi ? U1[mt][c] : U1[mt][c + 1];
        const unsigned got0 = permx32(snd0);
        const unsigned got1 = permx32(snd1);
        union { unsigned u[4]; short8 s; } ap;
        ap.u[0] = hi ? got0 : own0;
        ap.u[1] = hi ? got1 : own1;
        ap.u[2] = hi ? own0 : got0;
        ap.u[3] = hi ? own1 : got1;
        // V B-frag from registers (R3/R5-validated): own quad==2hi supplies
        // rows 16kt+8hi+{0..3}; lane^16 rows +{4..7}. Lanes lo>=16 feed B
        // cols >=16 whose outputs are discarded.
        union { unsigned u[4]; short8 s; } bvf;
        bvf.u[0] = pv[2 * kt];
        bvf.u[1] = pv[2 * kt + 1];
        bvf.u[2] = __shfl_xor(pv[2 * kt], 16);
        bvf.u[3] = __shfl_xor(pv[2 * kt + 1], 16);
        if (kt & 1)
          oaccB = MFMA32(ap.s, bvf.s, oaccB);
        else
          oaccA = MFMA32(ap.s, bvf.s, oaccA);
      }
      if (lo < HD) {
#pragma unroll
        for (int r = 0; r < 16; ++r) {
          const int rr = (r & 3) + 8 * (r >> 2) + 4 * hi;
          if (qt0 + rr < CC)
            qoh[(qt0 + rr) * HD + lo] = f2bf(oaccA[r] + oaccB[r]);
        }
      }
    }
  }
  __syncthreads();

  // ---- phase C: out-proj + residual + LN. waves 0..6, M-tile = wave ----
  if (wave < 7) {
    const int mt = wave;
    const u16* __restrict__ w_bo = w_b + 3 * 16384;
    short8 A[4];
#pragma unroll
    for (int kf = 0; kf < 4; ++kf) {
      // O(c, kf*32+quad*8..) lives at QO[head][c][j0], head=2kf+(quad>>1)
      const int head = 2 * kf + (quad >> 1);
      A[kf] =
          *(const short8*)&QO[head * QS + (mt * 16 + n) * HD + (quad & 1) * 8];
    }
    float v[8][4];
#pragma unroll
    for (int nt = 0; nt < 8; ++nt) {
      const int col = nt * 16 + n;
      const float bcol = bo[col];
      // R13: bias folded into accumulator init
      f32x4 acc = {bcol, bcol, bcol, bcol};
#pragma unroll
      for (int kf = 0; kf < 4; ++kf) {
        const short8 Bf =
            *(const short8*)(w_bo + (nt * 16 + n) * DD + kf * 32 + quad * 8);
        acc = MFMA16(A[kf], Bf, acc);
      }
#pragma unroll
      for (int r = 0; r < 4; ++r)
        v[nt][r] =
            acc[r] +
            bf2f(src_b[((size_t)b * CC + mt * 16 + quad * 4 + r) * DD + col]);
    }
    float sum[4] = {0.f, 0.f, 0.f, 0.f}, sq[4] = {0.f, 0.f, 0.f, 0.f};
#pragma unroll
    for (int nt = 0; nt < 8; ++nt)
#pragma unroll
      for (int r = 0; r < 4; ++r) {
        sum[r] += v[nt][r];
        sq[r] = fmaf(v[nt][r], v[nt][r], sq[r]);
      }
#pragma unroll
    for (int d = 1; d < 16; d <<= 1)
#pragma unroll
      for (int r = 0; r < 4; ++r) {
        sum[r] += __shfl_xor(sum[r], d);
        sq[r] += __shfl_xor(sq[r], d);
      }
    float mu[4], rs[4];
#pragma unroll
    for (int r = 0; r < 4; ++r) {
      mu[r] = sum[r] * (1.f / DD);
      const float var = sq[r] * (1.f / DD) - mu[r] * mu[r];
      rs[r] = rsqrtf(var + 1e-5f);
    }
#pragma unroll
    for (int nt = 0; nt < 8; ++nt) {
      const int col = nt * 16 + n;
      const float g = lg[col], be = lb[col];
#pragma unroll
      for (int r = 0; r < 4; ++r)
        out[((size_t)b * CC + mt * 16 + quad * 4 + r) * DD + col] =
            (v[nt][r] - mu[r]) * rs[r] * g + be;
    }
  }
}

extern "C" void kernel_launch(void* const* d_in, const int* in_sizes, int n_in,
                              void* d_out, int out_size, void* d_ws,
                              size_t ws_size, hipStream_t stream) {
  (void)in_sizes; (void)n_in; (void)out_size; (void)ws_size;
  const float* x   = (const float*)d_in[0];
  const float* cw  = (const float*)d_in[1];
  const float* cb  = (const float*)d_in[2];
  const float* bg  = (const float*)d_in[3];
  const float* bb  = (const float*)d_in[4];
  const float* bm  = (const float*)d_in[5];
  const float* bv  = (const float*)d_in[6];
  const float* wq  = (const float*)d_in[7];
  const float* bq  = (const float*)d_in[8];
  const float* wk  = (const float*)d_in[9];
  const float* bk  = (const float*)d_in[10];
  const float* wv  = (const float*)d_in[11];
  const float* bvv = (const float*)d_in[12];
  const float* wo  = (const float*)d_in[13];
  const float* bo  = (const float*)d_in[14];
  const float* lg  = (const float*)d_in[15];
  const float* lb  = (const float*)d_in[16];
  float* out = (float*)d_out;

  const size_t NE = (size_t)BB * CC * DD;  // 7,340,032
  u16* ub = (u16*)d_ws;
  u16* src_b = ub;       // bf16 src, row-major [B*C, D]
  u16* w_b   = ub + NE;  // 4 x 128x128 bf16 weights (q,k,v,o)

  k_conv<<<2 * BB, 256, 0, stream>>>(x, cw, cb, bg, bb, bm, bv, wq, wk, wv,
                                     wo, src_b, w_b);
  k_main<<<BB, 512, 0, stream>>>(src_b, w_b, bq, bk, bvv, bo, lg, lb, out);
}

// Round 14
// 168.584 us; speedup vs baseline: 1.0128x; 1.0128x over previous
//
#include <hip/hip_runtime.h>
#include <hip/hip_bf16.h>

#define BB 512
#define CC 112
#define DD 128
#define HH 8
#define HD 16
#define KK 8
#define QS 1792  // per-head u16 stride in QO/KL (112*16)

typedef unsigned short u16;
typedef short short8 __attribute__((ext_vector_type(8)));
typedef float f32x4 __attribute__((ext_vector_type(4)));
typedef float f32x16 __attribute__((ext_vector_type(16)));

#define MFMA16(a, b, c) __builtin_amdgcn_mfma_f32_16x16x32_bf16(a, b, c, 0, 0, 0)
#define MFMA32(a, b, c) __builtin_amdgcn_mfma_f32_32x32x16_bf16(a, b, c, 0, 0, 0)

__device__ inline u16 f2bf(float f) {
  union { float f; unsigned u; } v{f};
  unsigned r = (v.u + 0x7FFFu + ((v.u >> 16) & 1u)) >> 16;
  return (u16)r;
}
__device__ inline float bf2f(u16 u) {
  union { unsigned u; float f; } v;
  v.u = ((unsigned)u) << 16;
  return v.f;
}
__device__ inline unsigned pk2(float a, float b) {
  __hip_bfloat162 h = __float22bfloat162_rn(float2{a, b});
  union { __hip_bfloat162 h; unsigned u; } v{h};
  return v.u;
}

// lane[i] <-> lane[i^32] exchange via v_permlane32_swap_b32 (VALU, no LDS
// pipe). Validated on-harness R1-R7, R11, R12.
__device__ inline unsigned permx32(unsigned x) {
  unsigned a = x, b = x;
  asm("v_permlane32_swap_b32 %0, %1" : "+v"(a), "+v"(b));
  return (threadIdx.x & 32) ? a : b;
}
__device__ inline float permx32f(float x) {
  union { float f; unsigned u; } v{x};
  v.u = permx32(v.u);
  return v.f;
}

// ---------------------------------------------------------------------------
// K1: conv+GELU+BN+residual -> bf16 src_b (global). 1024 blocks x 256 thr
// (2 blocks/batch, 56 rows each; R11/R12-validated). Threads 224..255 of
// each block convert 32 weight fp32-pairs -> bf16 w_b (1024 x 32 = 32768).
// ---------------------------------------------------------------------------
__global__ __launch_bounds__(256, 4) void k_conv(
    const float* __restrict__ x, const float* __restrict__ cw,
    const float* __restrict__ cb, const float* __restrict__ bg,
    const float* __restrict__ bb_, const float* __restrict__ bm,
    const float* __restrict__ bv, const float* __restrict__ wq,
    const float* __restrict__ wk, const float* __restrict__ wv,
    const float* __restrict__ wo, u16* __restrict__ src_b,
    u16* __restrict__ w_b) {
  const int bid = blockIdx.x;
  const int b = bid >> 1, half = bid & 1;
  const int t = threadIdx.x;
  const int tg = t >> 2, sub = t & 3;
  if (tg < 56) {
    const int row = half * 56 + tg, ch = row;
    const float4 w0 = *(const float4*)(cw + ch * KK);
    const float4 w1 = *(const float4*)(cw + ch * KK + 4);
    const float cbv = cb[ch];
    const float bscale = bg[ch] * rsqrtf(bv[ch] + 1e-5f);
    const float bmv = bm[ch], bbv = bb_[ch];
    const float* __restrict__ xr = x + ((size_t)b * CC + row) * DD;
    float in[40];  // cols sub*32-4 .. sub*32+35
#pragma unroll
    for (int f = 0; f < 10; ++f) {
      const int fi = 8 * sub - 1 + f;
      float4 vv = {0.f, 0.f, 0.f, 0.f};
      if (fi >= 0 && fi < 32) vv = ((const float4*)xr)[fi];
      in[f * 4 + 0] = vv.x; in[f * 4 + 1] = vv.y;
      in[f * 4 + 2] = vv.z; in[f * 4 + 3] = vv.w;
    }
    unsigned pkv[16];
#pragma unroll
    for (int i2 = 0; i2 < 16; ++i2) {
      float oo[2];
#pragma unroll
      for (int j = 0; j < 2; ++j) {
        const int i = i2 * 2 + j;
        float a = 0.f;
        a = fmaf(in[i + 1], w0.x, a);
        a = fmaf(in[i + 2], w0.y, a);
        a = fmaf(in[i + 3], w0.z, a);
        a = fmaf(in[i + 4], w0.w, a);
        a = fmaf(in[i + 5], w1.x, a);
        a = fmaf(in[i + 6], w1.y, a);
        a = fmaf(in[i + 7], w1.z, a);
        a = fmaf(in[i + 8], w1.w, a);
        a += cbv;
        // GELU tanh-form via sigma (validated, absmax unchanged)
        const float u = fmaf(0.044715f * a, a, 1.0f);
        const float e = __expf(a * u * -1.5957691216f);
        const float g2 = a * __frcp_rn(1.f + e);
        oo[j] = in[i + 4] + (g2 - bmv) * bscale + bbv;  // x + BN(GELU)
      }
      pkv[i2] = pk2(oo[0], oo[1]);
    }
    uint4* gsr = (uint4*)(src_b + ((size_t)b * CC + row) * DD + sub * 32);
#pragma unroll
    for (int k4 = 0; k4 < 4; ++k4) gsr[k4] = ((uint4*)pkv)[k4];
  } else if (t >= 224) {
    // weight conversion: pair index p covers 2 floats.
    const int p = bid * 32 + (t - 224);       // [0, 32768)
    const int sel = p >> 13, off = p & 8191;  // matrix, pair-within-matrix
    const float* w = (sel == 0) ? wq : (sel == 1) ? wk : (sel == 2) ? wv : wo;
    const float2 v = ((const float2*)w)[off];
    ((unsigned*)w_b)[p] = pk2(v.x, v.y);
  }
}

// ---------------------------------------------------------------------------
// K2: QKV + attention + out-proj + LN, one block per batch, 512 thr = 8
// waves, LDS 57.3 KB -> 2 blocks/CU, all 512 blocks resident (one round).
// R12 (S4) core BYTE-IDENTICAL in numerics (absmax 0.043, twice-validated;
// R13's bias-fold/dual-acc reorder regressed dur AND pushed absmax to the
// threshold edge -- reverted). R14 delta: s_setprio(1)/(0) brackets around
// the four MFMA-dense regions (T5). Mechanism match: phases A/B run
// barrier-free so the 16 resident waves/CU drift out of phase -- the CU
// scheduler has real role diversity to arbitrate (m191-style, not the m190
// lockstep null). Scheduling hint only; numerics untouched.
// ---------------------------------------------------------------------------
__global__ __launch_bounds__(512, 4) void k_main(
    const u16* __restrict__ src_b, const u16* __restrict__ w_b,
    const float* __restrict__ bq, const float* __restrict__ bk,
    const float* __restrict__ bvv, const float* __restrict__ bo,
    const float* __restrict__ lg, const float* __restrict__ lb,
    float* __restrict__ out) {
  __shared__ __attribute__((aligned(16))) u16 QO[HH * CC * HD];  // 28672 B
  __shared__ __attribute__((aligned(16))) u16 KL[HH * CC * HD];  // 28672 B
  const int b = blockIdx.x;
  const int t = threadIdx.x;
  const int wave = t >> 6, lane = t & 63;
  const int h = wave;
  const int quad = lane >> 4, n = lane & 15;

  // ---- phase A: QKV ----
  unsigned pv[14];
  {
    short8 Wq[4], Wk[4], Wv[4];
#pragma unroll
    for (int kf = 0; kf < 4; ++kf) {
      const int wi = (h * 16 + n) * DD + kf * 32 + quad * 8;
      Wq[kf] = *(const short8*)(w_b + wi);
      Wk[kf] = *(const short8*)(w_b + 16384 + wi);
      Wv[kf] = *(const short8*)(w_b + 32768 + wi);
    }
    const float bqv = bq[h * 16 + n];
    const float bkv = bk[h * 16 + n];
    const float bvv2 = bvv[h * 16 + n];
    u16* qoh = QO + h * QS;
    u16* klh = KL + h * QS;
    const u16* __restrict__ sp = src_b + (size_t)b * CC * DD;
#pragma unroll
    for (int mt = 0; mt < 7; ++mt) {
      short8 A[4];
#pragma unroll
      for (int kf = 0; kf < 4; ++kf)
        A[kf] = *(const short8*)(sp + (mt * 16 + n) * DD + kf * 32 + quad * 8);
      f32x4 aq = {0.f, 0.f, 0.f, 0.f};
      f32x4 ak = {0.f, 0.f, 0.f, 0.f};
      f32x4 av = {0.f, 0.f, 0.f, 0.f};
      __builtin_amdgcn_s_setprio(1);  // T5: MFMA-dense region
#pragma unroll
      for (int kf = 0; kf < 4; ++kf) {
        aq = MFMA16(A[kf], Wq[kf], aq);
        ak = MFMA16(A[kf], Wk[kf], ak);
        av = MFMA16(A[kf], Wv[kf], av);
      }
      __builtin_amdgcn_s_setprio(0);
      const int row0 = mt * 16 + quad * 4;
#pragma unroll
      for (int r = 0; r < 4; ++r) {
        qoh[(row0 + r) * HD + n] = f2bf(aq[r] + bqv);
        klh[(row0 + r) * HD + n] = f2bf(ak[r] + bkv);
      }
      // V rows 16mt+4quad+{0..3}, col n stay in regs as bf16 pairs
      pv[2 * mt] = pk2(av[0] + bvv2, av[1] + bvv2);
      pv[2 * mt + 1] = pk2(av[2] + bvv2, av[3] + bvv2);
    }
  }

  // ---- phase B: attention (no barrier needed: Q/K/V self-produced) ----
  {
    const int lo = lane & 31, hi = lane >> 5, hi8 = hi * 8;
    u16* qoh = QO + h * QS;
    const u16* klh = KL + h * QS;
    for (int qt = 0; qt < 4; ++qt) {
      const int qt0 = qt * 32;
      short8 Bq = {};
      if (qt0 + lo < CC) Bq = *(const short8*)(qoh + (qt0 + lo) * HD + hi8);
      f32x16 sa[4];
      __builtin_amdgcn_s_setprio(1);  // T5: score MFMA cluster
#pragma unroll
      for (int mt = 0; mt < 4; ++mt) {
        short8 Ak = {};
        const int key = mt * 32 + lo;
        if (key < CC) Ak = *(const short8*)(klh + key * HD + hi8);
        f32x16 z = {};
        sa[mt] = MFMA32(Ak, Bq, z);
      }
      __builtin_amdgcn_s_setprio(0);
      // lane holds S^T[key=32mt+(r&3)+8(r>>2)+4hi][query=qt0+lo];
      // valid: mt<3 all regs, mt=3 regs 0..7 (keys 96..111).
      const float C1 = 0.25f * 1.44269504088896341f;  // SCALE * log2(e)
      float mxp[4] = {-1e30f, -1e30f, -1e30f, -1e30f};  // 4-way ILP chains
#pragma unroll
      for (int mt = 0; mt < 4; ++mt) {
        const int rmax = (mt == 3) ? 8 : 16;
#pragma unroll
        for (int r = 0; r < 16; ++r)
          if (r < rmax) mxp[r & 3] = fmaxf(mxp[r & 3], sa[mt][r]);
      }
      float mx = fmaxf(fmaxf(mxp[0], mxp[1]), fmaxf(mxp[2], mxp[3]));
      mx = fmaxf(mx, permx32f(mx));
      const float mxc = mx * C1;
      float sp4[4] = {0.f, 0.f, 0.f, 0.f};
#pragma unroll
      for (int mt = 0; mt < 4; ++mt) {
        const int rmax = (mt == 3) ? 8 : 16;
#pragma unroll
        for (int r = 0; r < 16; ++r)
          if (r < rmax) {
            const float p = exp2f(fmaf(sa[mt][r], C1, -mxc));
            sa[mt][r] = p;
            sp4[r & 3] += p;
          }
      }
      float sum = (sp4[0] + sp4[1]) + (sp4[2] + sp4[3]);
      sum += permx32f(sum);
      const float rinv = 1.f / sum;
      unsigned U0[4][4], U1[4][4];
#pragma unroll
      for (int mt = 0; mt < 4; ++mt) {
        const int rqmax = (mt == 3) ? 2 : 4;
#pragma unroll
        for (int rq = 0; rq < 4; ++rq)
          if (rq < rqmax) {
            U0[mt][rq] =
                pk2(sa[mt][4 * rq + 0] * rinv, sa[mt][4 * rq + 1] * rinv);
            U1[mt][rq] =
                pk2(sa[mt][4 * rq + 2] * rinv, sa[mt][4 * rq + 3] * rinv);
          }
      }
      f32x16 oacc = {};
      __builtin_amdgcn_s_setprio(1);  // T5: PV MFMA chain
#pragma unroll
      for (int kt = 0; kt < 7; ++kt) {
        const int mt = kt >> 1;
        const int c = 2 * (kt & 1);
        const unsigned own0 = hi ? U0[mt][c + 1] : U0[mt][c];
        const unsigned own1 = hi ? U1[mt][c + 1] : U1[mt][c];
        const unsigned snd0 = hi ? U0[mt][c] : U0[mt][c + 1];
        const unsigned snd1 = hi ? U1[mt][c] : U1[mt][c + 1];
        const unsigned got0 = permx32(snd0);
        const unsigned got1 = permx32(snd1);
        union { unsigned u[4]; short8 s; } ap;
        ap.u[0] = hi ? got0 : own0;
        ap.u[1] = hi ? got1 : own1;
        ap.u[2] = hi ? own0 : got0;
        ap.u[3] = hi ? own1 : got1;
        // V B-frag from registers (R3/R5-validated): own quad==2hi supplies
        // rows 16kt+8hi+{0..3}; lane^16 rows +{4..7}. Lanes lo>=16 feed B
        // cols >=16 whose outputs are discarded.
        union { unsigned u[4]; short8 s; } bvf;
        bvf.u[0] = pv[2 * kt];
        bvf.u[1] = pv[2 * kt + 1];
        bvf.u[2] = __shfl_xor(pv[2 * kt], 16);
        bvf.u[3] = __shfl_xor(pv[2 * kt + 1], 16);
        oacc = MFMA32(ap.s, bvf.s, oacc);
      }
      __builtin_amdgcn_s_setprio(0);
      if (lo < HD) {
#pragma unroll
        for (int r = 0; r < 16; ++r) {
          const int rr = (r & 3) + 8 * (r >> 2) + 4 * hi;
          if (qt0 + rr < CC) qoh[(qt0 + rr) * HD + lo] = f2bf(oacc[r]);
        }
      }
    }
  }
  __syncthreads();

  // ---- phase C: out-proj + residual + LN. waves 0..6, M-tile = wave ----
  if (wave < 7) {
    const int mt = wave;
    const u16* __restrict__ w_bo = w_b + 3 * 16384;
    short8 A[4];
#pragma unroll
    for (int kf = 0; kf < 4; ++kf) {
      // O(c, kf*32+quad*8..) lives at QO[head][c][j0], head=2kf+(quad>>1)
      const int head = 2 * kf + (quad >> 1);
      A[kf] =
          *(const short8*)&QO[head * QS + (mt * 16 + n) * HD + (quad & 1) * 8];
    }
    float v[8][4];
#pragma unroll
    for (int nt = 0; nt < 8; ++nt) {
      f32x4 acc = {0.f, 0.f, 0.f, 0.f};
      __builtin_amdgcn_s_setprio(1);  // T5: out-proj MFMA cluster
#pragma unroll
      for (int kf = 0; kf < 4; ++kf) {
        const short8 Bf =
            *(const short8*)(w_bo + (nt * 16 + n) * DD + kf * 32 + quad * 8);
        acc = MFMA16(A[kf], Bf, acc);
      }
      __builtin_amdgcn_s_setprio(0);
      const int col = nt * 16 + n;
      const float bcol = bo[col];
#pragma unroll
      for (int r = 0; r < 4; ++r)
        v[nt][r] =
            acc[r] + bcol +
            bf2f(src_b[((size_t)b * CC + mt * 16 + quad * 4 + r) * DD + col]);
    }
    float sum[4] = {0.f, 0.f, 0.f, 0.f}, sq[4] = {0.f, 0.f, 0.f, 0.f};
#pragma unroll
    for (int nt = 0; nt < 8; ++nt)
#pragma unroll
      for (int r = 0; r < 4; ++r) {
        sum[r] += v[nt][r];
        sq[r] = fmaf(v[nt][r], v[nt][r], sq[r]);
      }
#pragma unroll
    for (int d = 1; d < 16; d <<= 1)
#pragma unroll
      for (int r = 0; r < 4; ++r) {
        sum[r] += __shfl_xor(sum[r], d);
        sq[r] += __shfl_xor(sq[r], d);
      }
    float mu[4], rs[4];
#pragma unroll
    for (int r = 0; r < 4; ++r) {
      mu[r] = sum[r] * (1.f / DD);
      const float var = sq[r] * (1.f / DD) - mu[r] * mu[r];
      rs[r] = rsqrtf(var + 1e-5f);
    }
#pragma unroll
    for (int nt = 0; nt < 8; ++nt) {
      const int col = nt * 16 + n;
      const float g = lg[col], be = lb[col];
#pragma unroll
      for (int r = 0; r < 4; ++r)
        out[((size_t)b * CC + mt * 16 + quad * 4 + r) * DD + col] =
            (v[nt][r] - mu[r]) * rs[r] * g + be;
    }
  }
}

extern "C" void kernel_launch(void* const* d_in, const int* in_sizes, int n_in,
                              void* d_out, int out_size, void* d_ws,
                              size_t ws_size, hipStream_t stream) {
  (void)in_sizes; (void)n_in; (void)out_size; (void)ws_size;
  const float* x   = (const float*)d_in[0];
  const float* cw  = (const float*)d_in[1];
  const float* cb  = (const float*)d_in[2];
  const float* bg  = (const float*)d_in[3];
  const float* bb  = (const float*)d_in[4];
  const float* bm  = (const float*)d_in[5];
  const float* bv  = (const float*)d_in[6];
  const float* wq  = (const float*)d_in[7];
  const float* bq  = (const float*)d_in[8];
  const float* wk  = (const float*)d_in[9];
  const float* bk  = (const float*)d_in[10];
  const float* wv  = (const float*)d_in[11];
  const float* bvv = (const float*)d_in[12];
  const float* wo  = (const float*)d_in[13];
  const float* bo  = (const float*)d_in[14];
  const float* lg  = (const float*)d_in[15];
  const float* lb  = (const float*)d_in[16];
  float* out = (float*)d_out;

  const size_t NE = (size_t)BB * CC * DD;  // 7,340,032
  u16* ub = (u16*)d_ws;
  u16* src_b = ub;       // bf16 src, row-major [B*C, D]
  u16* w_b   = ub + NE;  // 4 x 128x128 bf16 weights (q,k,v,o)

  k_conv<<<2 * BB, 256, 0, stream>>>(x, cw, cb, bg, bb, bm, bv, wq, wk, wv,
                                     wo, src_b, w_b);
  k_main<<<BB, 512, 0, stream>>>(src_b, w_b, bq, bk, bvv, bo, lg, lb, out);
}

// Round 15
// 167.935 us; speedup vs baseline: 1.0168x; 1.0039x over previous
//
#include <hip/hip_runtime.h>
#include <hip/hip_bf16.h>

#define BB 512
#define CC 112
#define DD 128
#define HH 8
#define HD 16
#define KK 8
#define QS 1792  // per-head u16 stride in QO/KL (112*16)

typedef unsigned short u16;
typedef short short8 __attribute__((ext_vector_type(8)));
typedef float f32x4 __attribute__((ext_vector_type(4)));
typedef float f32x16 __attribute__((ext_vector_type(16)));

#define MFMA16(a, b, c) __builtin_amdgcn_mfma_f32_16x16x32_bf16(a, b, c, 0, 0, 0)
#define MFMA32(a, b, c) __builtin_amdgcn_mfma_f32_32x32x16_bf16(a, b, c, 0, 0, 0)

__device__ inline u16 f2bf(float f) {
  union { float f; unsigned u; } v{f};
  unsigned r = (v.u + 0x7FFFu + ((v.u >> 16) & 1u)) >> 16;
  return (u16)r;
}
__device__ inline float bf2f(u16 u) {
  union { unsigned u; float f; } v;
  v.u = ((unsigned)u) << 16;
  return v.f;
}
__device__ inline unsigned pk2(float a, float b) {
  __hip_bfloat162 h = __float22bfloat162_rn(float2{a, b});
  union { __hip_bfloat162 h; unsigned u; } v{h};
  return v.u;
}

// lane[i] <-> lane[i^32] exchange via v_permlane32_swap_b32 (VALU, no LDS
// pipe). Validated on-harness R1-R7, R11, R12, R14.
__device__ inline unsigned permx32(unsigned x) {
  unsigned a = x, b = x;
  asm("v_permlane32_swap_b32 %0, %1" : "+v"(a), "+v"(b));
  return (threadIdx.x & 32) ? a : b;
}
__device__ inline float permx32f(float x) {
  union { float f; unsigned u; } v{x};
  v.u = permx32(v.u);
  return v.f;
}

// ---------------------------------------------------------------------------
// K1: conv+GELU+BN+residual -> bf16 src_b (global). 1024 blocks x 256 thr
// (2 blocks/batch, 56 rows each; R11/R12/R14-validated). Threads 224..255 of
// each block convert 32 weight fp32-pairs -> bf16 w_b (1024 x 32 = 32768).
// ---------------------------------------------------------------------------
__global__ __launch_bounds__(256, 4) void k_conv(
    const float* __restrict__ x, const float* __restrict__ cw,
    const float* __restrict__ cb, const float* __restrict__ bg,
    const float* __restrict__ bb_, const float* __restrict__ bm,
    const float* __restrict__ bv, const float* __restrict__ wq,
    const float* __restrict__ wk, const float* __restrict__ wv,
    const float* __restrict__ wo, u16* __restrict__ src_b,
    u16* __restrict__ w_b) {
  const int bid = blockIdx.x;
  const int b = bid >> 1, half = bid & 1;
  const int t = threadIdx.x;
  const int tg = t >> 2, sub = t & 3;
  if (tg < 56) {
    const int row = half * 56 + tg, ch = row;
    const float4 w0 = *(const float4*)(cw + ch * KK);
    const float4 w1 = *(const float4*)(cw + ch * KK + 4);
    const float cbv = cb[ch];
    const float bscale = bg[ch] * rsqrtf(bv[ch] + 1e-5f);
    const float bmv = bm[ch], bbv = bb_[ch];
    const float* __restrict__ xr = x + ((size_t)b * CC + row) * DD;
    float in[40];  // cols sub*32-4 .. sub*32+35
#pragma unroll
    for (int f = 0; f < 10; ++f) {
      const int fi = 8 * sub - 1 + f;
      float4 vv = {0.f, 0.f, 0.f, 0.f};
      if (fi >= 0 && fi < 32) vv = ((const float4*)xr)[fi];
      in[f * 4 + 0] = vv.x; in[f * 4 + 1] = vv.y;
      in[f * 4 + 2] = vv.z; in[f * 4 + 3] = vv.w;
    }
    unsigned pkv[16];
#pragma unroll
    for (int i2 = 0; i2 < 16; ++i2) {
      float oo[2];
#pragma unroll
      for (int j = 0; j < 2; ++j) {
        const int i = i2 * 2 + j;
        float a = 0.f;
        a = fmaf(in[i + 1], w0.x, a);
        a = fmaf(in[i + 2], w0.y, a);
        a = fmaf(in[i + 3], w0.z, a);
        a = fmaf(in[i + 4], w0.w, a);
        a = fmaf(in[i + 5], w1.x, a);
        a = fmaf(in[i + 6], w1.y, a);
        a = fmaf(in[i + 7], w1.z, a);
        a = fmaf(in[i + 8], w1.w, a);
        a += cbv;
        // GELU tanh-form via sigma (validated, absmax unchanged)
        const float u = fmaf(0.044715f * a, a, 1.0f);
        const float e = __expf(a * u * -1.5957691216f);
        const float g2 = a * __frcp_rn(1.f + e);
        oo[j] = in[i + 4] + (g2 - bmv) * bscale + bbv;  // x + BN(GELU)
      }
      pkv[i2] = pk2(oo[0], oo[1]);
    }
    uint4* gsr = (uint4*)(src_b + ((size_t)b * CC + row) * DD + sub * 32);
#pragma unroll
    for (int k4 = 0; k4 < 4; ++k4) gsr[k4] = ((uint4*)pkv)[k4];
  } else if (t >= 224) {
    // weight conversion: pair index p covers 2 floats.
    const int p = bid * 32 + (t - 224);       // [0, 32768)
    const int sel = p >> 13, off = p & 8191;  // matrix, pair-within-matrix
    const float* w = (sel == 0) ? wq : (sel == 1) ? wk : (sel == 2) ? wv : wo;
    const float2 v = ((const float2*)w)[off];
    ((unsigned*)w_b)[p] = pk2(v.x, v.y);
  }
}

// ---------------------------------------------------------------------------
// K2: QKV + attention + out-proj + LN, one block per batch, 512 thr = 8
// waves, LDS 57.3 KB -> 2 blocks/CU, all 512 blocks resident (one round).
// R14 core (S4 numerics + T5 setprio brackets, 59.3 us measured, absmax
// 0.0430) + R15 delta: per-wave query-tile ROTATION (qt = (qi+wave)&3).
// Each wave owns all 4 qt of its own head, so iteration order is free;
// rotating by wave index staggers each wave's score-MFMA cluster vs its
// softmax VALU/TRANS burst relative to SIMD neighbors -> less same-pipe
// collision, more role diversity for setprio to arbitrate. Numerics are
// bit-identical per qt (same ops, same order within a tile).
// ---------------------------------------------------------------------------
__global__ __launch_bounds__(512, 4) void k_main(
    const u16* __restrict__ src_b, const u16* __restrict__ w_b,
    const float* __restrict__ bq, const float* __restrict__ bk,
    const float* __restrict__ bvv, const float* __restrict__ bo,
    const float* __restrict__ lg, const float* __restrict__ lb,
    float* __restrict__ out) {
  __shared__ __attribute__((aligned(16))) u16 QO[HH * CC * HD];  // 28672 B
  __shared__ __attribute__((aligned(16))) u16 KL[HH * CC * HD];  // 28672 B
  const int b = blockIdx.x;
  const int t = threadIdx.x;
  const int wave = t >> 6, lane = t & 63;
  const int h = wave;
  const int quad = lane >> 4, n = lane & 15;

  // ---- phase A: QKV ----
  unsigned pv[14];
  {
    short8 Wq[4], Wk[4], Wv[4];
#pragma unroll
    for (int kf = 0; kf < 4; ++kf) {
      const int wi = (h * 16 + n) * DD + kf * 32 + quad * 8;
      Wq[kf] = *(const short8*)(w_b + wi);
      Wk[kf] = *(const short8*)(w_b + 16384 + wi);
      Wv[kf] = *(const short8*)(w_b + 32768 + wi);
    }
    const float bqv = bq[h * 16 + n];
    const float bkv = bk[h * 16 + n];
    const float bvv2 = bvv[h * 16 + n];
    u16* qoh = QO + h * QS;
    u16* klh = KL + h * QS;
    const u16* __restrict__ sp = src_b + (size_t)b * CC * DD;
#pragma unroll
    for (int mt = 0; mt < 7; ++mt) {
      short8 A[4];
#pragma unroll
      for (int kf = 0; kf < 4; ++kf)
        A[kf] = *(const short8*)(sp + (mt * 16 + n) * DD + kf * 32 + quad * 8);
      f32x4 aq = {0.f, 0.f, 0.f, 0.f};
      f32x4 ak = {0.f, 0.f, 0.f, 0.f};
      f32x4 av = {0.f, 0.f, 0.f, 0.f};
      __builtin_amdgcn_s_setprio(1);  // T5: MFMA-dense region
#pragma unroll
      for (int kf = 0; kf < 4; ++kf) {
        aq = MFMA16(A[kf], Wq[kf], aq);
        ak = MFMA16(A[kf], Wk[kf], ak);
        av = MFMA16(A[kf], Wv[kf], av);
      }
      __builtin_amdgcn_s_setprio(0);
      const int row0 = mt * 16 + quad * 4;
#pragma unroll
      for (int r = 0; r < 4; ++r) {
        qoh[(row0 + r) * HD + n] = f2bf(aq[r] + bqv);
        klh[(row0 + r) * HD + n] = f2bf(ak[r] + bkv);
      }
      // V rows 16mt+4quad+{0..3}, col n stay in regs as bf16 pairs
      pv[2 * mt] = pk2(av[0] + bvv2, av[1] + bvv2);
      pv[2 * mt + 1] = pk2(av[2] + bvv2, av[3] + bvv2);
    }
  }

  // ---- phase B: attention (no barrier needed: Q/K/V self-produced) ----
  {
    const int lo = lane & 31, hi = lane >> 5, hi8 = hi * 8;
    u16* qoh = QO + h * QS;
    const u16* klh = KL + h * QS;
    for (int qi = 0; qi < 4; ++qi) {
      // R15: per-wave rotation staggers pipe usage across SIMD neighbors.
      const int qt = (qi + wave) & 3;
      const int qt0 = qt * 32;
      short8 Bq = {};
      if (qt0 + lo < CC) Bq = *(const short8*)(qoh + (qt0 + lo) * HD + hi8);
      f32x16 sa[4];
      __builtin_amdgcn_s_setprio(1);  // T5: score MFMA cluster
#pragma unroll
      for (int mt = 0; mt < 4; ++mt) {
        short8 Ak = {};
        const int key = mt * 32 + lo;
        if (key < CC) Ak = *(const short8*)(klh + key * HD + hi8);
        f32x16 z = {};
        sa[mt] = MFMA32(Ak, Bq, z);
      }
      __builtin_amdgcn_s_setprio(0);
      // lane holds S^T[key=32mt+(r&3)+8(r>>2)+4hi][query=qt0+lo];
      // valid: mt<3 all regs, mt=3 regs 0..7 (keys 96..111).
      const float C1 = 0.25f * 1.44269504088896341f;  // SCALE * log2(e)
      float mxp[4] = {-1e30f, -1e30f, -1e30f, -1e30f};  // 4-way ILP chains
#pragma unroll
      for (int mt = 0; mt < 4; ++mt) {
        const int rmax = (mt == 3) ? 8 : 16;
#pragma unroll
        for (int r = 0; r < 16; ++r)
          if (r < rmax) mxp[r & 3] = fmaxf(mxp[r & 3], sa[mt][r]);
      }
      float mx = fmaxf(fmaxf(mxp[0], mxp[1]), fmaxf(mxp[2], mxp[3]));
      mx = fmaxf(mx, permx32f(mx));
      const float mxc = mx * C1;
      float sp4[4] = {0.f, 0.f, 0.f, 0.f};
#pragma unroll
      for (int mt = 0; mt < 4; ++mt) {
        const int rmax = (mt == 3) ? 8 : 16;
#pragma unroll
        for (int r = 0; r < 16; ++r)
          if (r < rmax) {
            const float p = exp2f(fmaf(sa[mt][r], C1, -mxc));
            sa[mt][r] = p;
            sp4[r & 3] += p;
          }
      }
      float sum = (sp4[0] + sp4[1]) + (sp4[2] + sp4[3]);
      sum += permx32f(sum);
      const float rinv = 1.f / sum;
      unsigned U0[4][4], U1[4][4];
#pragma unroll
      for (int mt = 0; mt < 4; ++mt) {
        const int rqmax = (mt == 3) ? 2 : 4;
#pragma unroll
        for (int rq = 0; rq < 4; ++rq)
          if (rq < rqmax) {
            U0[mt][rq] =
                pk2(sa[mt][4 * rq + 0] * rinv, sa[mt][4 * rq + 1] * rinv);
            U1[mt][rq] =
                pk2(sa[mt][4 * rq + 2] * rinv, sa[mt][4 * rq + 3] * rinv);
          }
      }
      f32x16 oacc = {};
      __builtin_amdgcn_s_setprio(1);  // T5: PV MFMA chain
#pragma unroll
      for (int kt = 0; kt < 7; ++kt) {
        const int mt = kt >> 1;
        const int c = 2 * (kt & 1);
        const unsigned own0 = hi ? U0[mt][c + 1] : U0[mt][c];
        const unsigned own1 = hi ? U1[mt][c + 1] : U1[mt][c];
        const unsigned snd0 = hi ? U0[mt][c] : U0[mt][c + 1];
        const unsigned snd1 = hi ? U1[mt][c] : U1[mt][c + 1];
        const unsigned got0 = permx32(snd0);
        const unsigned got1 = permx32(snd1);
        union { unsigned u[4]; short8 s; } ap;
        ap.u[0] = hi ? got0 : own0;
        ap.u[1] = hi ? got1 : own1;
        ap.u[2] = hi ? own0 : got0;
        ap.u[3] = hi ? own1 : got1;
        // V B-frag from registers (R3/R5-validated): own quad==2hi supplies
        // rows 16kt+8hi+{0..3}; lane^16 rows +{4..7}. Lanes lo>=16 feed B
        // cols >=16 whose outputs are discarded.
        union { unsigned u[4]; short8 s; } bvf;
        bvf.u[0] = pv[2 * kt];
        bvf.u[1] = pv[2 * kt + 1];
        bvf.u[2] = __shfl_xor(pv[2 * kt], 16);
        bvf.u[3] = __shfl_xor(pv[2 * kt + 1], 16);
        oacc = MFMA32(ap.s, bvf.s, oacc);
      }
      __builtin_amdgcn_s_setprio(0);
      if (lo < HD) {
#pragma unroll
        for (int r = 0; r < 16; ++r) {
          const int rr = (r & 3) + 8 * (r >> 2) + 4 * hi;
          if (qt0 + rr < CC) qoh[(qt0 + rr) * HD + lo] = f2bf(oacc[r]);
        }
      }
    }
  }
  __syncthreads();

  // ---- phase C: out-proj + residual + LN. waves 0..6, M-tile = wave ----
  if (wave < 7) {
    const int mt = wave;
    const u16* __restrict__ w_bo = w_b + 3 * 16384;
    short8 A[4];
#pragma unroll
    for (int kf = 0; kf < 4; ++kf) {
      // O(c, kf*32+quad*8..) lives at QO[head][c][j0], head=2kf+(quad>>1)
      const int head = 2 * kf + (quad >> 1);
      A[kf] =
          *(const short8*)&QO[head * QS + (mt * 16 + n) * HD + (quad & 1) * 8];
    }
    float v[8][4];
#pragma unroll
    for (int nt = 0; nt < 8; ++nt) {
      f32x4 acc = {0.f, 0.f, 0.f, 0.f};
      __builtin_amdgcn_s_setprio(1);  // T5: out-proj MFMA cluster
#pragma unroll
      for (int kf = 0; kf < 4; ++kf) {
        const short8 Bf =
            *(const short8*)(w_bo + (nt * 16 + n) * DD + kf * 32 + quad * 8);
        acc = MFMA16(A[kf], Bf, acc);
      }
      __builtin_amdgcn_s_setprio(0);
      const int col = nt * 16 + n;
      const float bcol = bo[col];
#pragma unroll
      for (int r = 0; r < 4; ++r)
        v[nt][r] =
            acc[r] + bcol +
            bf2f(src_b[((size_t)b * CC + mt * 16 + quad * 4 + r) * DD + col]);
    }
    float sum[4] = {0.f, 0.f, 0.f, 0.f}, sq[4] = {0.f, 0.f, 0.f, 0.f};
#pragma unroll
    for (int nt = 0; nt < 8; ++nt)
#pragma unroll
      for (int r = 0; r < 4; ++r) {
        sum[r] += v[nt][r];
        sq[r] = fmaf(v[nt][r], v[nt][r], sq[r]);
      }
#pragma unroll
    for (int d = 1; d < 16; d <<= 1)
#pragma unroll
      for (int r = 0; r < 4; ++r) {
        sum[r] += __shfl_xor(sum[r], d);
        sq[r] += __shfl_xor(sq[r], d);
      }
    float mu[4], rs[4];
#pragma unroll
    for (int r = 0; r < 4; ++r) {
      mu[r] = sum[r] * (1.f / DD);
      const float var = sq[r] * (1.f / DD) - mu[r] * mu[r];
      rs[r] = rsqrtf(var + 1e-5f);
    }
#pragma unroll
    for (int nt = 0; nt < 8; ++nt) {
      const int col = nt * 16 + n;
      const float g = lg[col], be = lb[col];
#pragma unroll
      for (int r = 0; r < 4; ++r)
        out[((size_t)b * CC + mt * 16 + quad * 4 + r) * DD + col] =
            (v[nt][r] - mu[r]) * rs[r] * g + be;
    }
  }
}

extern "C" void kernel_launch(void* const* d_in, const int* in_sizes, int n_in,
                              void* d_out, int out_size, void* d_ws,
                              size_t ws_size, hipStream_t stream) {
  (void)in_sizes; (void)n_in; (void)out_size; (void)ws_size;
  const float* x   = (const float*)d_in[0];
  const float* cw  = (const float*)d_in[1];
  const float* cb  = (const float*)d_in[2];
  const float* bg  = (const float*)d_in[3];
  const float* bb  = (const float*)d_in[4];
  const float* bm  = (const float*)d_in[5];
  const float* bv  = (const float*)d_in[6];
  const float* wq  = (const float*)d_in[7];
  const float* bq  = (const float*)d_in[8];
  const float* wk  = (const float*)d_in[9];
  const float* bk  = (const float*)d_in[10];
  const float* wv  = (const float*)d_in[11];
  const float* bvv = (const float*)d_in[12];
  const float* wo  = (const float*)d_in[13];
  const float* bo  = (const float*)d_in[14];
  const float* lg  = (const float*)d_in[15];
  const float* lb  = (const float*)d_in[16];
  float* out = (float*)d_out;

  const size_t NE = (size_t)BB * CC * DD;  // 7,340,032
  u16* ub = (u16*)d_ws;
  u16* src_b = ub;       // bf16 src, row-major [B*C, D]
  u16* w_b   = ub + NE;  // 4 x 128x128 bf16 weights (q,k,v,o)

  k_conv<<<2 * BB, 256, 0, stream>>>(x, cw, cb, bg, bb, bm, bv, wq, wk, wv,
                                     wo, src_b, w_b);
  k_main<<<BB, 512, 0, stream>>>(src_b, w_b, bq, bk, bvv, bo, lg, lb, out);
}